// Round 8
// baseline (113.118 us; speedup 1.0000x reference)
//
#include <hip/hip_runtime.h>
#include <math.h>

// Round-19: r18 post-mortem: product 38.2->34.3 (SELPAY+remat removal
// confirmed) but 48KB LDS -> 12-wave cap -> occupancy 26%, busy 75.5%.
// This round: 20-row LDS hybrid = 40KB -> EXACTLY 4 blocks/CU (160KB),
// 16-wave cap (+33% waves).
//  - rows 0..19 hold slots 4..23 (c2 corners + 16 intersections);
//    row = slot - 4. c1 corners (slots 0..3) stay in regs (needed for the
//    gather anyway): 4-way cndmask tree = 6 inst + 2 selects per gather
//    (~64 inst total, vs r16's 300-inst 8-way tree + remat).
//  - latency reorder: SORT8(0) placed while intersection read batch A is
//    in flight, SORT8(8) while batch B is in flight (sort work hides LDS
//    round-trip latency; zero inst cost).
//  - area1/area2 computed early so pw/ph/qw/qh die before the sort.
// Row stride 2048B == 0 mod 128 -> bank = f(lane) only -> conflict-free
// for dynamic rows; per-thread column -> no barriers.
// FROZEN (bit-critical): atan2f/cosf/sinf + __f*_rn corner chain, mask
// ratios, masked sx/sy sum order, centroid FDIV, key function, cross order.

#define FMUL __fmul_rn
#define FADD __fadd_rn
#define FSUB __fsub_rn
#define FDIV __fdiv_rn

__device__ __forceinline__ float rcpf_(float x) { return __builtin_amdgcn_rcpf(x); }

// compare-exchange on packed keys: min -> pk[A], max -> pk[B]
#define CE(A,B) do { unsigned _x = pk[A], _y = pk[B]; \
                     pk[A] = _x < _y ? _x : _y; pk[B] = _x < _y ? _y : _x; } while (0)

// Batcher odd-even mergesort of pk[o..o+7], 19 CE
#define SORT8(o) do { \
    CE(o+0,o+1); CE(o+2,o+3); CE(o+0,o+2); CE(o+1,o+3); CE(o+1,o+2); \
    CE(o+4,o+5); CE(o+6,o+7); CE(o+4,o+6); CE(o+5,o+7); CE(o+5,o+6); \
    CE(o+0,o+4); CE(o+1,o+5); CE(o+2,o+6); CE(o+3,o+7); \
    CE(o+2,o+4); CE(o+3,o+5); \
    CE(o+1,o+2); CE(o+3,o+4); CE(o+5,o+6); } while (0)

// pk[0..7] sorted asc, pk[o..o+7] sorted asc ->
// pk[0..7] = lowest 8 of the 16, sorted (half-cleaner + bitonic-8).
#define MERGE_LOW8(o) do { \
    CE(0,o+7); CE(1,o+6); CE(2,o+5); CE(3,o+4); \
    CE(4,o+3); CE(5,o+2); CE(6,o+1); CE(7,o+0); \
    CE(0,4); CE(1,5); CE(2,6); CE(3,7); \
    CE(0,2); CE(1,3); CE(4,6); CE(5,7); \
    CE(0,1); CE(2,3); CE(4,5); CE(6,7); } while (0)

// u32 packed key (27-bit diamond-angle | 5-bit slot), monotone in atan2.
#define MAKEKEY(J, WX, WY, M, DST) do {                                     \
    float _dsum = FADD(fabsf(WX), fabsf(WY));                               \
    float _rs = (_dsum > 0.0f) ? FMUL((WX), rcpf_(_dsum)) : 1.0f;           \
    float _keyf = copysignf(FSUB(1.0f, _rs), (WY));                         \
    unsigned _sbk = __float_as_uint(_keyf);                                 \
    unsigned _u = _sbk ^ (unsigned)(((int)_sbk >> 31) | (int)0x80000000);   \
    (DST) = (M) ? ((_u & 0xFFFFFFE0u) | (unsigned)(J))                      \
                : (0xFFFFFFE0u | (unsigned)(J));                            \
} while (0)

// Payload for dynamic slot: slot>=4 -> VI (read from LDS row slot-4);
// slot<4 -> 4-way cndmask tree over c1 corner regs (2 bits).
#define SELPAY4(SLOT, VI, OUTX, OUTY) do {                                  \
    unsigned _sl = (SLOT);                                                  \
    bool _b0 = (_sl & 1u) != 0u, _b1 = (_sl & 2u) != 0u;                    \
    float _l0x = _b0 ? c1x[1] : c1x[0], _l0y = _b0 ? c1y[1] : c1y[0];       \
    float _l1x = _b0 ? c1x[3] : c1x[2], _l1y = _b0 ? c1y[3] : c1y[2];       \
    float _cx = _b1 ? _l1x : _l0x, _cy = _b1 ? _l1y : _l0y;                 \
    bool _isC = _sl < 4u;                                                   \
    (OUTX) = _isC ? _cx : (VI).x;                                           \
    (OUTY) = _isC ? _cy : (VI).y;                                           \
} while (0)

__global__
__attribute__((amdgpu_flat_work_group_size(256, 256), amdgpu_waves_per_eu(1)))
void riou_kernel(const float* __restrict__ pred,
                 const float* __restrict__ tgt,
                 float* __restrict__ out, int n)
{
    // rows 0..3 = c2 corners (slots 4..7), rows 4..19 = intersections
    // (slots 8..23). row = slot - 4. 40KB -> exactly 4 blocks/CU.
    __shared__ float2 vlds[20][256];
    const int tid = threadIdx.x;
    int i = blockIdx.x * blockDim.x + tid;
    if (i >= n) return;

    const float2* p2 = (const float2*)(pred + 6 * (size_t)i);
    const float2* q2 = (const float2*)(tgt  + 6 * (size_t)i);
    float2 pa = p2[0], pb = p2[1], pc2 = p2[2];
    float2 qa = q2[0], qb = q2[1], qc2 = q2[2];
    const float px = pa.x, py = pa.y, pw = pb.x, ph = pb.y;
    const float qx = qa.x, qy = qa.y, qw = qb.x, qh = qb.y;

    // areas early: pw/ph/qw/qh die before the sort (live-set trim)
    float area1 = FMUL(pw, ph), area2 = FMUL(qw, qh);

    // bit-critical transcendental sequence — DO NOT substitute identities
    float rad1 = atan2f(pc2.x, pc2.y);
    float cA = cosf(rad1), sA = sinf(rad1);
    float rad2 = atan2f(qc2.x, qc2.y);
    float cB = cosf(rad2), sB = sinf(rad2);

    const float ddx[4] = {0.5f, -0.5f, -0.5f, 0.5f};
    const float ddy[4] = {0.5f, 0.5f, -0.5f, -0.5f};
    float c1x[4], c1y[4], c2x[4], c2y[4];
#pragma unroll
    for (int j = 0; j < 4; j++) {
        float cx = FMUL(ddx[j], pw), cy = FMUL(ddy[j], ph);
        c1x[j] = FADD(FSUB(FMUL(cx, cA), FMUL(cy, sA)), px);
        c1y[j] = FADD(FADD(FMUL(cx, sA), FMUL(cy, cA)), py);
        float dx2 = FMUL(ddx[j], qw), dy2 = FMUL(ddy[j], qh);
        c2x[j] = FADD(FSUB(FMUL(dx2, cB), FMUL(dy2, sB)), qx);
        c2y[j] = FADD(FADD(FMUL(dx2, sB), FMUL(dy2, cB)), qy);
        vlds[j][tid] = make_float2(c2x[j], c2y[j]);   // slot 4+j -> row j
    }

    // enclosing-box diagonal + center distance
    float minx = c1x[0], maxx = c1x[0], miny = c1y[0], maxy = c1y[0];
#pragma unroll
    for (int j = 1; j < 4; j++) {
        minx = fminf(minx, c1x[j]); maxx = fmaxf(maxx, c1x[j]);
        miny = fminf(miny, c1y[j]); maxy = fmaxf(maxy, c1y[j]);
    }
#pragma unroll
    for (int j = 0; j < 4; j++) {
        minx = fminf(minx, c2x[j]); maxx = fmaxf(maxx, c2x[j]);
        miny = fminf(miny, c2y[j]); maxy = fmaxf(maxy, c2y[j]);
    }
    float wcb = FSUB(maxx, minx), hcb = FSUB(maxy, miny);
    float c2d = FADD(FMUL(wcb, wcb), FMUL(hcb, hcb));
    float dxc = FSUB(px, qx), dyc = FSUB(py, qy);
    float d2 = FADD(FMUL(dxc, dxc), FMUL(dyc, dyc));

    // ---- phase 1: 24 candidate slots, mask bits + masked sums ----
    unsigned mbits = 0;
    float sx = 0.0f, sy = 0.0f;
    const float eps = 1e-6f;
    const float hieps = 1.0f + 1e-6f;

    // slots 0-3: c1 corners inside c2
    {
        float ax = c2x[0], ay = c2y[0];
        float abx = FSUB(c2x[1], ax), aby = FSUB(c2y[1], ay);
        float adx = FSUB(c2x[3], ax), ady = FSUB(c2y[3], ay);
        float rab = rcpf_(FADD(FMUL(abx, abx), FMUL(aby, aby)));
        float rad = rcpf_(FADD(FMUL(adx, adx), FMUL(ady, ady)));
#pragma unroll
        for (int j = 0; j < 4; j++) {
            float amx = FSUB(c1x[j], ax), amy = FSUB(c1y[j], ay);
            float pab = FMUL(FADD(FMUL(abx, amx), FMUL(aby, amy)), rab);
            float pad = FMUL(FADD(FMUL(adx, amx), FMUL(ady, amy)), rad);
            int m = (pab > -eps) & (pab < hieps) & (pad > -eps) & (pad < hieps);
            mbits |= (unsigned)m << j;
            sx = FADD(sx, m ? c1x[j] : 0.0f);
            sy = FADD(sy, m ? c1y[j] : 0.0f);
        }
    }
    // slots 4-7: c2 corners inside c1
    {
        float ax = c1x[0], ay = c1y[0];
        float abx = FSUB(c1x[1], ax), aby = FSUB(c1y[1], ay);
        float adx = FSUB(c1x[3], ax), ady = FSUB(c1y[3], ay);
        float rab = rcpf_(FADD(FMUL(abx, abx), FMUL(aby, aby)));
        float rad = rcpf_(FADD(FMUL(adx, adx), FMUL(ady, ady)));
#pragma unroll
        for (int j = 0; j < 4; j++) {
            float amx = FSUB(c2x[j], ax), amy = FSUB(c2y[j], ay);
            float pab = FMUL(FADD(FMUL(abx, amx), FMUL(aby, amy)), rab);
            float pad = FMUL(FADD(FMUL(adx, amx), FMUL(ady, amy)), rad);
            int m = (pab > -eps) & (pab < hieps) & (pad > -eps) & (pad < hieps);
            mbits |= (unsigned)m << (4 + j);
            sx = FADD(sx, m ? c2x[j] : 0.0f);
            sy = FADD(sy, m ? c2y[j] : 0.0f);
        }
    }
    // slots 8-23: edge intersections; den_u = -den_t exactly -> one rcp.
    float fex[4], fey[4];
#pragma unroll
    for (int e2 = 0; e2 < 4; e2++) {
        fex[e2] = FSUB(c2x[(e2 + 1) & 3], c2x[e2]);
        fey[e2] = FSUB(c2y[(e2 + 1) & 3], c2y[e2]);
    }
#pragma unroll
    for (int e1 = 0; e1 < 4; e1++) {
        float x1 = c1x[e1], y1 = c1y[e1];
        float ex = FSUB(c1x[(e1 + 1) & 3], x1), ey = FSUB(c1y[(e1 + 1) & 3], y1);
#pragma unroll
        for (int e2 = 0; e2 < 4; e2++) {
            float dx31 = FSUB(c2x[e2], x1), dy31 = FSUB(c2y[e2], y1);
            float num_t = FSUB(FMUL(ex, dy31), FMUL(ey, dx31));
            float den_t = FSUB(FMUL(ey, fex[e2]), FMUL(ex, fey[e2]));
            float rd = rcpf_(den_t);          // den==0 -> inf -> masked below
            float tq = FMUL(num_t, rd);
            float num_u = FSUB(FMUL(fey[e2], dx31), FMUL(fex[e2], dy31));
            float uq = FMUL(num_u, rd);       // == -u exactly
            int m = (tq > 0.0f) & (tq < 1.0f) & (uq < 0.0f) & (uq > -1.0f);
            float ix = FADD(x1, FMUL(tq, ex));   // garbage if masked; gated
            float iy = FADD(y1, FMUL(tq, ey));
            int s = 4 * e1 + e2;
            vlds[4 + s][tid] = make_float2(ix, iy);   // slot 8+s -> row 4+s
            mbits |= (unsigned)m << (8 + s);
            sx = FADD(sx, m ? ix : 0.0f);
            sy = FADD(sy, m ? iy : 0.0f);
        }
    }

    int k = __popc(mbits);

    // centroid (IEEE div: feeds every recentered coordinate — bit-frozen)
    float kk = (float)(k > 0 ? k : 1);
    float mx = FDIV(sx, kk), my = FDIV(sy, kk);

    // ---- phase 2: keys, with sort work interleaved to hide LDS latency.
    // Corner keys use regs (c1,c2 still live -> identical bits).
    unsigned pk[24];
    float2 va[8];
#pragma unroll
    for (int j = 0; j < 8; j++) va[j] = vlds[4 + j][tid];    // slots 8..15
#pragma unroll
    for (int j = 0; j < 8; j++) {                            // corners
        float rx = (j < 4) ? c1x[j] : c2x[j - 4];
        float ry = (j < 4) ? c1y[j] : c2y[j - 4];
        int m = (mbits >> j) & 1u;
        float wx2 = FSUB(rx, mx);
        float wy2 = FSUB(ry, my);
        MAKEKEY(j, wx2, wy2, m, pk[j]);
    }
    SORT8(0);                       // pure VALU while batch A is in flight
#pragma unroll
    for (int j = 8; j < 16; j++) {                           // slots 8..15
        int m = (mbits >> j) & 1u;
        float wx2 = FSUB(va[j - 8].x, mx);
        float wy2 = FSUB(va[j - 8].y, my);
        MAKEKEY(j, wx2, wy2, m, pk[j]);
    }
#pragma unroll
    for (int j = 0; j < 8; j++) va[j] = vlds[12 + j][tid];   // slots 16..23
    SORT8(8);                       // pure VALU while batch B is in flight
#pragma unroll
    for (int j = 16; j < 24; j++) {
        int m = (mbits >> j) & 1u;
        float wx2 = FSUB(va[j - 16].x, mx);
        float wy2 = FSUB(va[j - 16].y, my);
        MAKEKEY(j, wx2, wy2, m, pk[j]);
    }
    // c2 corner registers die here; c1 stays for the gather tree.

    SORT8(16);
    MERGE_LOW8(8);
    MERGE_LOW8(16);

    // ---- phase 3: batch-issue 8 dynamic gathers (row = slot-4), walk ----
    float2 vi[8];
#pragma unroll
    for (int s = 0; s < 8; s++) {
        int ls = (int)(pk[s] & 31u) - 4;
        ls = ls < 0 ? 0 : ls;               // c1 slots read row 0 (discarded)
        vi[s] = vlds[ls][tid];              // dynamic row: conflict-free
    }

    float firstx = 0.0f, firsty = 0.0f, prevx = 0.0f, prevy = 0.0f;
    float crs = 0.0f;
#pragma unroll
    for (int s = 0; s < 8; s++) {
        unsigned slot = pk[s] & 31u;
        float rxv, ryv;
        SELPAY4(slot, vi[s], rxv, ryv);
        float gx = FSUB(rxv, mx);
        float gy = FSUB(ryv, my);
        bool act = s < k;                  // inactive pass: payload -> prev
        float bx = act ? gx : prevx;
        float by = act ? gy : prevy;
        if (s == 0) { firstx = bx; firsty = by; }
        else {
            // inactive: cross(prev,prev) = exact IEEE 0 (identical products)
            crs = FADD(crs, FSUB(FMUL(prevx, by), FMUL(prevy, bx)));
        }
        prevx = bx; prevy = by;
    }
    // rare tail: noise masks can push k past the geometric bound of 8.
    // Leftovers in pk[8..23] all exceed pk[7] -> successive minima continue
    // the ascending order; keys unique -> sentinel removal removes one.
    if (k > 8) {
        for (int s = 8; s < k; s++) {
            unsigned mn = pk[8];
#pragma unroll
            for (int j = 9; j < 24; j++) mn = (pk[j] < mn) ? pk[j] : mn;
            unsigned slot = mn & 31u;
            int ls = (int)slot - 4;
            ls = ls < 0 ? 0 : ls;
            float2 vt = vlds[ls][tid];
            float rxv, ryv;
            SELPAY4(slot, vt, rxv, ryv);
            float bx = FSUB(rxv, mx);
            float by = FSUB(ryv, my);
            crs = FADD(crs, FSUB(FMUL(prevx, by), FMUL(prevy, bx)));
            prevx = bx; prevy = by;
#pragma unroll
            for (int j = 8; j < 24; j++) if (pk[j] == mn) pk[j] = 0xFFFFFFFFu;
        }
    }
    // close the ring
    crs = FADD(crs, FSUB(FMUL(prevx, firsty), FMUL(prevy, firstx)));
    float inter = FMUL(0.5f, fabsf(crs));

    float uni = FSUB(FADD(area1, area2), inter);
    float iou = FMUL(inter, rcpf_(uni));

    out[i] = FADD(FSUB(1.0f, iou), FMUL(d2, rcpf_(c2d)));
}

extern "C" void kernel_launch(void* const* d_in, const int* in_sizes, int n_in,
                              void* d_out, int out_size, void* d_ws, size_t ws_size,
                              hipStream_t stream) {
    const float* pred = (const float*)d_in[0];
    const float* tgt  = (const float*)d_in[1];
    float* out = (float*)d_out;
    int n = in_sizes[0] / 6;
    int block = 256;
    int grid = (n + block - 1) / block;
    riou_kernel<<<grid, block, 0, stream>>>(pred, tgt, out, n);
}

// Round 9
// 111.408 us; speedup vs baseline: 1.0153x; 1.0153x over previous
//
#include <hip/hip_runtime.h>
#include <math.h>

// Round-20: r19 falsifier fired: occupancy 26->33% left VALUBusy flat (~76)
// -> issue-bandwidth-saturated; only instruction count moves duration.
// Base = r18 (lowest product 34.3: row==slot all-LDS payload, no gather
// tree). Change: packed-f32 (v_pk_add/mul_f32, full-rate on gfx90a+) via
// ext_vector float2 for every cleanly pairable (x,y) chain — per-lane IEEE
// rounding identical to scalar -> BIT-EXACT. Pairable: corner-gen partials,
// box-test vectors+dot partials, intersection d31/lerp, masked sums (sx,sy
// as one pair), all recenters, walk selects. Cross-product reductions and
// mixed add/sub lanes stay scalar (packing them costs moves). ~180 VALU
// inst removed (~13%). Plus r19's free sort/read interleave + early areas.
// Worst case (backend scalarizes): neutral and still bit-identical.
// FROZEN (bit-critical): atan2f/cosf/sinf + __f*_rn corner chain, mask
// ratios, masked sx/sy sum order, centroid FDIV, key function, cross order.

#define FMUL __fmul_rn
#define FADD __fadd_rn
#define FSUB __fsub_rn
#define FDIV __fdiv_rn

typedef float v2f __attribute__((ext_vector_type(2)));
__device__ __forceinline__ v2f v2(float a, float b) { v2f r; r.x = a; r.y = b; return r; }

__device__ __forceinline__ float rcpf_(float x) { return __builtin_amdgcn_rcpf(x); }

// compare-exchange on packed keys: min -> pk[A], max -> pk[B]
#define CE(A,B) do { unsigned _x = pk[A], _y = pk[B]; \
                     pk[A] = _x < _y ? _x : _y; pk[B] = _x < _y ? _y : _x; } while (0)

// Batcher odd-even mergesort of pk[o..o+7], 19 CE
#define SORT8(o) do { \
    CE(o+0,o+1); CE(o+2,o+3); CE(o+0,o+2); CE(o+1,o+3); CE(o+1,o+2); \
    CE(o+4,o+5); CE(o+6,o+7); CE(o+4,o+6); CE(o+5,o+7); CE(o+5,o+6); \
    CE(o+0,o+4); CE(o+1,o+5); CE(o+2,o+6); CE(o+3,o+7); \
    CE(o+2,o+4); CE(o+3,o+5); \
    CE(o+1,o+2); CE(o+3,o+4); CE(o+5,o+6); } while (0)

// pk[0..7] sorted asc, pk[o..o+7] sorted asc ->
// pk[0..7] = lowest 8 of the 16, sorted (half-cleaner + bitonic-8).
#define MERGE_LOW8(o) do { \
    CE(0,o+7); CE(1,o+6); CE(2,o+5); CE(3,o+4); \
    CE(4,o+3); CE(5,o+2); CE(6,o+1); CE(7,o+0); \
    CE(0,4); CE(1,5); CE(2,6); CE(3,7); \
    CE(0,2); CE(1,3); CE(4,6); CE(5,7); \
    CE(0,1); CE(2,3); CE(4,5); CE(6,7); } while (0)

// u32 packed key (27-bit diamond-angle | 5-bit slot), monotone in atan2.
#define MAKEKEY(J, WX, WY, M, DST) do {                                     \
    float _dsum = FADD(fabsf(WX), fabsf(WY));                               \
    float _rs = (_dsum > 0.0f) ? FMUL((WX), rcpf_(_dsum)) : 1.0f;           \
    float _keyf = copysignf(FSUB(1.0f, _rs), (WY));                         \
    unsigned _sbk = __float_as_uint(_keyf);                                 \
    unsigned _u = _sbk ^ (unsigned)(((int)_sbk >> 31) | (int)0x80000000);   \
    (DST) = (M) ? ((_u & 0xFFFFFFE0u) | (unsigned)(J))                      \
                : (0xFFFFFFE0u | (unsigned)(J));                            \
} while (0)

__global__
__attribute__((amdgpu_flat_work_group_size(256, 256), amdgpu_waves_per_eu(1)))
void riou_kernel(const float* __restrict__ pred,
                 const float* __restrict__ tgt,
                 float* __restrict__ out, int n)
{
    // row == slot: 0..3 c1 corners, 4..7 c2 corners, 8..23 intersections.
    // Row stride 2048B == 0 mod 128 -> bank = f(lane) only -> conflict-free
    // for dynamic rows; per-thread column -> no barriers. 48KB/block.
    __shared__ v2f vlds[24][256];
    const int tid = threadIdx.x;
    int i = blockIdx.x * blockDim.x + tid;
    if (i >= n) return;

    const float2* p2 = (const float2*)(pred + 6 * (size_t)i);
    const float2* q2 = (const float2*)(tgt  + 6 * (size_t)i);
    float2 pa = p2[0], pb = p2[1], pc2 = p2[2];
    float2 qa = q2[0], qb = q2[1], qc2 = q2[2];
    const float px = pa.x, py = pa.y, pw = pb.x, ph = pb.y;
    const float qx = qa.x, qy = qa.y, qw = qb.x, qh = qb.y;

    // areas early: pw/ph/qw/qh die sooner (live-set trim)
    float area1 = FMUL(pw, ph), area2 = FMUL(qw, qh);

    // bit-critical transcendental sequence — DO NOT substitute identities
    float rad1 = atan2f(pc2.x, pc2.y);
    float cA = cosf(rad1), sA = sinf(rad1);
    float rad2 = atan2f(qc2.x, qc2.y);
    float cB = cosf(rad2), sB = sinf(rad2);

    // dd[j] = (ddx[j], ddy[j])
    const v2f dd[4] = { v2(0.5f, 0.5f), v2(-0.5f, 0.5f),
                        v2(-0.5f, -0.5f), v2(0.5f, -0.5f) };
    const v2f pwh = v2(pw, ph), qwh = v2(qw, qh);
    const v2f pxy = v2(px, py), qxy = v2(qx, qy);
    const v2f rotA1 = v2(cA, sA), rotA2 = v2(sA, cA);
    const v2f rotB1 = v2(cB, sB), rotB2 = v2(sB, cB);

    v2f c1v[4], c2v[4];
#pragma unroll
    for (int j = 0; j < 4; j++) {
        v2f cc = dd[j] * pwh;                 // (cx, cy)  [pk_mul, exact]
        v2f t1 = cc * rotA1;                  // (cx*cA, cy*sA)
        v2f t2 = cc * rotA2;                  // (cx*sA, cy*cA)
        v2f u;                                // mixed sub/add lanes: scalar
        u.x = FSUB(t1.x, t1.y);
        u.y = FADD(t2.x, t2.y);
        c1v[j] = u + pxy;                     // pk_add, exact
        v2f dc = dd[j] * qwh;
        v2f t3 = dc * rotB1;
        v2f t4 = dc * rotB2;
        v2f w;
        w.x = FSUB(t3.x, t3.y);
        w.y = FADD(t4.x, t4.y);
        c2v[j] = w + qxy;
        vlds[j][tid]     = c1v[j];            // slot j
        vlds[4 + j][tid] = c2v[j];            // slot 4+j
    }

    // enclosing-box diagonal + center distance (same op order as before)
    float minx = c1v[0].x, maxx = c1v[0].x, miny = c1v[0].y, maxy = c1v[0].y;
#pragma unroll
    for (int j = 1; j < 4; j++) {
        minx = fminf(minx, c1v[j].x); maxx = fmaxf(maxx, c1v[j].x);
        miny = fminf(miny, c1v[j].y); maxy = fmaxf(maxy, c1v[j].y);
    }
#pragma unroll
    for (int j = 0; j < 4; j++) {
        minx = fminf(minx, c2v[j].x); maxx = fmaxf(maxx, c2v[j].x);
        miny = fminf(miny, c2v[j].y); maxy = fmaxf(maxy, c2v[j].y);
    }
    float wcb = FSUB(maxx, minx), hcb = FSUB(maxy, miny);
    float c2d = FADD(FMUL(wcb, wcb), FMUL(hcb, hcb));
    float dxc = FSUB(px, qx), dyc = FSUB(py, qy);
    float d2 = FADD(FMUL(dxc, dxc), FMUL(dyc, dyc));

    // ---- phase 1: 24 candidate slots, mask bits + masked sums ----
    unsigned mbits = 0;
    v2f s2 = v2(0.0f, 0.0f);                 // (sx, sy) packed
    const v2f zero2 = v2(0.0f, 0.0f);
    const float eps = 1e-6f;
    const float hieps = 1.0f + 1e-6f;

    // slots 0-3: c1 corners inside c2
    {
        v2f a  = c2v[0];
        v2f ab = c2v[1] - a;                  // pk_sub, exact
        v2f ad = c2v[3] - a;
        v2f abab = ab * ab;
        float rab = rcpf_(FADD(abab.x, abab.y));
        v2f adad = ad * ad;
        float rad = rcpf_(FADD(adad.x, adad.y));
#pragma unroll
        for (int j = 0; j < 4; j++) {
            v2f am = c1v[j] - a;              // pk_sub
            v2f tb = ab * am;                 // pk_mul
            float pab = FMUL(FADD(tb.x, tb.y), rab);
            v2f td = ad * am;
            float pad = FMUL(FADD(td.x, td.y), rad);
            int m = (pab > -eps) & (pab < hieps) & (pad > -eps) & (pad < hieps);
            mbits |= (unsigned)m << j;
            s2 = s2 + (m ? c1v[j] : zero2);   // lane-wise FADD, same order
        }
    }
    // slots 4-7: c2 corners inside c1
    {
        v2f a  = c1v[0];
        v2f ab = c1v[1] - a;
        v2f ad = c1v[3] - a;
        v2f abab = ab * ab;
        float rab = rcpf_(FADD(abab.x, abab.y));
        v2f adad = ad * ad;
        float rad = rcpf_(FADD(adad.x, adad.y));
#pragma unroll
        for (int j = 0; j < 4; j++) {
            v2f am = c2v[j] - a;
            v2f tb = ab * am;
            float pab = FMUL(FADD(tb.x, tb.y), rab);
            v2f td = ad * am;
            float pad = FMUL(FADD(td.x, td.y), rad);
            int m = (pab > -eps) & (pab < hieps) & (pad > -eps) & (pad < hieps);
            mbits |= (unsigned)m << (4 + j);
            s2 = s2 + (m ? c2v[j] : zero2);
        }
    }
    // slots 8-23: edge intersections; den_u = -den_t exactly -> one rcp.
    v2f fe[4];
#pragma unroll
    for (int e2 = 0; e2 < 4; e2++) fe[e2] = c2v[(e2 + 1) & 3] - c2v[e2];
#pragma unroll
    for (int e1 = 0; e1 < 4; e1++) {
        v2f p1 = c1v[e1];
        v2f ev = c1v[(e1 + 1) & 3] - p1;      // pk_sub
#pragma unroll
        for (int e2 = 0; e2 < 4; e2++) {
            v2f d31 = c2v[e2] - p1;           // pk_sub
            // cross products: scalar (lane mixing would cost moves)
            float num_t = FSUB(FMUL(ev.x, d31.y), FMUL(ev.y, d31.x));
            float den_t = FSUB(FMUL(ev.y, fe[e2].x), FMUL(ev.x, fe[e2].y));
            float rd = rcpf_(den_t);          // den==0 -> inf -> masked below
            float tq = FMUL(num_t, rd);
            float num_u = FSUB(FMUL(fe[e2].y, d31.x), FMUL(fe[e2].x, d31.y));
            float uq = FMUL(num_u, rd);       // == -u exactly
            int m = (tq > 0.0f) & (tq < 1.0f) & (uq < 0.0f) & (uq > -1.0f);
            v2f ip = p1 + tq * ev;            // pk_mul(splat)+pk_add, exact
            int s = 4 * e1 + e2;
            vlds[8 + s][tid] = ip;            // slot 8+s == row 8+s
            mbits |= (unsigned)m << (8 + s);
            s2 = s2 + (m ? ip : zero2);
        }
    }

    int k = __popc(mbits);

    // centroid (IEEE div: feeds every recentered coordinate — bit-frozen)
    float kk = (float)(k > 0 ? k : 1);
    v2f m2 = v2(FDIV(s2.x, kk), FDIV(s2.y, kk));

    // ---- phase 2: keys, sort work interleaved to hide LDS latency ----
    unsigned pk[24];
    v2f va[8];
#pragma unroll
    for (int j = 0; j < 8; j++) va[j] = vlds[8 + j][tid];    // slots 8..15
#pragma unroll
    for (int j = 0; j < 8; j++) {                            // corners (regs)
        v2f w = ((j < 4) ? c1v[j] : c2v[j - 4]) - m2;        // pk_sub
        int m = (mbits >> j) & 1u;
        MAKEKEY(j, w.x, w.y, m, pk[j]);
    }
    SORT8(0);                       // pure VALU while batch A is in flight
#pragma unroll
    for (int j = 8; j < 16; j++) {                           // slots 8..15
        v2f w = va[j - 8] - m2;
        int m = (mbits >> j) & 1u;
        MAKEKEY(j, w.x, w.y, m, pk[j]);
    }
#pragma unroll
    for (int j = 0; j < 8; j++) va[j] = vlds[16 + j][tid];   // slots 16..23
    SORT8(8);                       // pure VALU while batch B is in flight
#pragma unroll
    for (int j = 16; j < 24; j++) {
        v2f w = va[j - 16] - m2;
        int m = (mbits >> j) & 1u;
        MAKEKEY(j, w.x, w.y, m, pk[j]);
    }
    // corner registers die here -> small live set across the sort.

    SORT8(16);
    MERGE_LOW8(8);
    MERGE_LOW8(16);

    // ---- phase 3: batch-issue 8 dynamic gathers (row == slot), walk ----
    v2f vi[8];
#pragma unroll
    for (int s = 0; s < 8; s++) {
        unsigned row = pk[s] & 31u;          // in [0,24): row == slot
        vi[s] = vlds[row][tid];              // dynamic row: conflict-free
    }

    v2f first2 = zero2, prev2 = zero2;
    float crs = 0.0f;
#pragma unroll
    for (int s = 0; s < 8; s++) {
        v2f g = vi[s] - m2;                  // pk_sub, exact recenter
        bool act = s < k;                    // inactive pass: payload -> prev
        v2f b = act ? g : prev2;
        if (s == 0) { first2 = b; }
        else {
            // inactive: cross(prev,prev) = exact IEEE 0 (identical products)
            crs = FADD(crs, FSUB(FMUL(prev2.x, b.y), FMUL(prev2.y, b.x)));
        }
        prev2 = b;
    }
    // rare tail: noise masks can push k past the geometric bound of 8.
    // Leftovers in pk[8..23] all exceed pk[7] -> successive minima continue
    // the ascending order; keys unique -> sentinel removal removes one.
    if (k > 8) {
        for (int s = 8; s < k; s++) {
            unsigned mn = pk[8];
#pragma unroll
            for (int j = 9; j < 24; j++) mn = (pk[j] < mn) ? pk[j] : mn;
            v2f vt = vlds[mn & 31u][tid];
            v2f b = vt - m2;
            crs = FADD(crs, FSUB(FMUL(prev2.x, b.y), FMUL(prev2.y, b.x)));
            prev2 = b;
#pragma unroll
            for (int j = 8; j < 24; j++) if (pk[j] == mn) pk[j] = 0xFFFFFFFFu;
        }
    }
    // close the ring
    crs = FADD(crs, FSUB(FMUL(prev2.x, first2.y), FMUL(prev2.y, first2.x)));
    float inter = FMUL(0.5f, fabsf(crs));

    float uni = FSUB(FADD(area1, area2), inter);
    float iou = FMUL(inter, rcpf_(uni));

    out[i] = FADD(FSUB(1.0f, iou), FMUL(d2, rcpf_(c2d)));
}

extern "C" void kernel_launch(void* const* d_in, const int* in_sizes, int n_in,
                              void* d_out, int out_size, void* d_ws, size_t ws_size,
                              hipStream_t stream) {
    const float* pred = (const float*)d_in[0];
    const float* tgt  = (const float*)d_in[1];
    float* out = (float*)d_out;
    int n = in_sizes[0] / 6;
    int block = 256;
    int grid = (n + block - 1) / block;
    riou_kernel<<<grid, block, 0, stream>>>(pred, tgt, out, n);
}